// Round 2
// baseline (25763.266 us; speedup 1.0000x reference)
//
#include <hip/hip_runtime.h>

// LSTM: B=8192, T=2048, D=1, H=256, C=10
// Persistent kernel: 256 WGs x 1024 threads (one per CU), 32 batch rows per WG.
// Recurrent GEMM per step: (32 x 256) @ (256 x 1024) via v_mfma_f32_16x16x32_f16.
// K-residency split (8 kk-groups of 32): kk=0 in VGPRs (16 regs), kk=1,2 in LDS
// (128 KB), kk=3..7 streamed from L2 each step (frag-ordered, 16B/lane, dbuf).
// h lives in LDS in MFMA-A-fragment order (conflict-free ds_read_b128);
// c persists in registers. __launch_bounds__(1024,4) -> 128-reg cap, no spills.
// d_ws: 512 KB fp16 B-frags, byte off = ((kk*16+w)*4+t)*1024 + lane*16.

#define BB 8192
#define TT 2048
#define HH 256
#define CC 10

typedef _Float16 half8 __attribute__((ext_vector_type(8)));
typedef float float4v __attribute__((ext_vector_type(4)));

#define LDS_W_BYTES   131072                  // kk=1,2
#define LDS_H_OFF     LDS_W_BYTES
#define LDS_H_BYTES   16384                   // 2 mt * 8 kk * 64 lane * 16 B
#define LDS_XS_OFF    (LDS_H_OFF + LDS_H_BYTES)
#define LDS_TOTAL     (LDS_XS_OFF + 32 * 4)   // 147584 bytes

__device__ __forceinline__ float frcp(float v)  { return __builtin_amdgcn_rcpf(v); }
__device__ __forceinline__ float fex2(float v)  { return __builtin_amdgcn_exp2f(v); }
// sigmoid(x) = 1/(1+2^(-x*log2e)) ; tanh(x) = 2*sigmoid(2x)-1
__device__ __forceinline__ float fsig(float v)  { return frcp(1.0f + fex2(-1.442695040888963f * v)); }
__device__ __forceinline__ float ftanh(float v) { return 2.0f * frcp(1.0f + fex2(-2.885390081777927f * v)) - 1.0f; }

// Pack W_{g,i,f,o}h (fp32 [256][256], row k, col j) into fp16 MFMA B-fragment order.
// 16B-unit u = ((kk*16 + w)*4 + t)*64 + lane ; element j of unit: k = kk*32 + (lane>>4)*8 + j,
// gate t, hidden col j_h = w*16 + (lane&15).
__global__ void pack_weights(const float* __restrict__ Wg, const float* __restrict__ Wi,
                             const float* __restrict__ Wf, const float* __restrict__ Wo,
                             _Float16* __restrict__ wsW) {
    int u = blockIdx.x * blockDim.x + threadIdx.x;   // 32768 units total
    int kk = u >> 12, rem = u & 4095;
    int w = rem >> 8, rem2 = rem & 255;
    int t = rem2 >> 6, lane = rem2 & 63;
    int q = lane >> 4, l15 = lane & 15;
    int jh = w * 16 + l15;
    const float* Wsrc = (t == 0) ? Wg : (t == 1) ? Wi : (t == 2) ? Wf : Wo;
    half8 v;
#pragma unroll
    for (int j = 0; j < 8; ++j) {
        int k = kk * 32 + q * 8 + j;
        v[j] = (_Float16)Wsrc[k * HH + jh];
    }
    ((half8*)wsW)[u] = v;
}

__global__ __launch_bounds__(1024, 4) void lstm_main(
    const float* __restrict__ x, const _Float16* __restrict__ wsW,
    const float* __restrict__ Wgx, const float* __restrict__ Wix,
    const float* __restrict__ Wfx, const float* __restrict__ Wox,
    const float* __restrict__ bg, const float* __restrict__ bi,
    const float* __restrict__ bfp, const float* __restrict__ bo,
    const float* __restrict__ Wp, const float* __restrict__ bp,
    float* __restrict__ out)
{
    extern __shared__ char smem[];
    _Float16* Wlds  = (_Float16*)smem;
    _Float16* hfrag = (_Float16*)(smem + LDS_H_OFF);
    float*    xs    = (float*)(smem + LDS_XS_OFF);

    const int tid  = threadIdx.x;
    const int w    = tid >> 6;
    const int lane = tid & 63;
    const int q    = lane >> 4;
    const int l15  = lane & 15;
    const int jh   = w * 16 + l15;       // this lane's hidden column (all 4 gates)
    const int b0   = blockIdx.x * 32;

    // ---- prologue ----
    for (int i = tid; i < LDS_H_BYTES / 2; i += 1024) hfrag[i] = (_Float16)0.f;  // h0 = 0
    if (tid < 32) xs[tid] = x[(b0 + tid) * TT + 0];
    {   // stage kk=1,2 weight frags into LDS (layout preserved)
        const uint4* src = (const uint4*)((const char*)wsW + 1 * 65536);
        uint4* dst = (uint4*)Wlds;
        for (int i = tid; i < LDS_W_BYTES / 16; i += 1024) dst[i] = src[i];
    }
    const char* wl = (const char*)wsW + w * 4096 + lane * 16;   // per-lane frag base
    half8 wr[4];                                                // kk=0 resident: 16 VGPRs
#pragma unroll
    for (int tt = 0; tt < 4; ++tt) wr[tt] = *(const half8*)(wl + tt * 1024);

    const float wxv[4] = { Wgx[jh], Wix[jh], Wfx[jh], Wox[jh] };
    const float bv[4]  = { bg[jh],  bi[jh],  bfp[jh], bo[jh]  };
    float4v cst[2]; cst[0] = (float4v){0.f,0.f,0.f,0.f}; cst[1] = (float4v){0.f,0.f,0.f,0.f};

    // h-write address precompute (frag-order scatter)
    const int kkw   = w >> 1;
    const int qp    = ((w & 1) << 1) | (l15 >> 3);
    const int j3    = l15 & 7;
    const int wbase = (kkw * 64 + qp * 16 + q * 4) * 8 + j3;    // + mt*4096 + r*8

    __syncthreads();

#define MFMA4(A0, A1, B0, B1, B2, B3)                                              \
    acc[0][0] = __builtin_amdgcn_mfma_f32_16x16x32_f16(A0, B0, acc[0][0], 0, 0, 0); \
    acc[1][0] = __builtin_amdgcn_mfma_f32_16x16x32_f16(A1, B0, acc[1][0], 0, 0, 0); \
    acc[0][1] = __builtin_amdgcn_mfma_f32_16x16x32_f16(A0, B1, acc[0][1], 0, 0, 0); \
    acc[1][1] = __builtin_amdgcn_mfma_f32_16x16x32_f16(A1, B1, acc[1][1], 0, 0, 0); \
    acc[0][2] = __builtin_amdgcn_mfma_f32_16x16x32_f16(A0, B2, acc[0][2], 0, 0, 0); \
    acc[1][2] = __builtin_amdgcn_mfma_f32_16x16x32_f16(A1, B2, acc[1][2], 0, 0, 0); \
    acc[0][3] = __builtin_amdgcn_mfma_f32_16x16x32_f16(A0, B3, acc[0][3], 0, 0, 0); \
    acc[1][3] = __builtin_amdgcn_mfma_f32_16x16x32_f16(A1, B3, acc[1][3], 0, 0, 0);

#define LOADG(dst, g)                                                              \
    dst[0] = *(const half8*)(wl + (g) * 65536 + 0 * 1024);                         \
    dst[1] = *(const half8*)(wl + (g) * 65536 + 1 * 1024);                         \
    dst[2] = *(const half8*)(wl + (g) * 65536 + 2 * 1024);                         \
    dst[3] = *(const half8*)(wl + (g) * 65536 + 3 * 1024);

#define AREAD(kkv, mtv) (*(const half8*)(hfrag + (mtv) * 4096 + (kkv) * 512 + lane * 8))

    // ---- time loop ----
#pragma unroll 1
    for (int ts = 0; ts < TT; ++ts) {
        half8 st0[4], st1[4];
        LOADG(st0, 3)
        LOADG(st1, 4)

        // prefetch next x (latency hidden under K-loop)
        float xnext = 0.f;
        int tn = (ts + 1 < TT) ? (ts + 1) : (TT - 1);
        if (tid < 32) xnext = x[(b0 + tid) * TT + tn];

        // acc init = bias + x_t * W_x  (fp32, exact)
        float4v acc[2][4];
#pragma unroll
        for (int mt = 0; mt < 2; ++mt) {
#pragma unroll
            for (int r = 0; r < 4; ++r) {
                float xvr = xs[mt * 16 + q * 4 + r];   // LDS broadcast
#pragma unroll
                for (int tt = 0; tt < 4; ++tt)
                    acc[mt][tt][r] = bv[tt] + xvr * wxv[tt];
            }
        }

        // K loop: kk=0 regs; kk=1,2 LDS; kk=3..7 streamed (double-buffered)
        {
            half8 a0, a1;
            a0 = AREAD(0, 0); a1 = AREAD(0, 1);
            MFMA4(a0, a1, wr[0], wr[1], wr[2], wr[3])
#pragma unroll
            for (int kk = 1; kk <= 2; ++kk) {
                const _Float16* wb = Wlds + (kk - 1) * 32768 + w * 2048 + lane * 8;
                a0 = AREAD(kk, 0); a1 = AREAD(kk, 1);
                MFMA4(a0, a1, *(const half8*)(wb), *(const half8*)(wb + 512),
                      *(const half8*)(wb + 1024), *(const half8*)(wb + 1536))
            }
            a0 = AREAD(3, 0); a1 = AREAD(3, 1);
            MFMA4(a0, a1, st0[0], st0[1], st0[2], st0[3])
            LOADG(st0, 5)
            a0 = AREAD(4, 0); a1 = AREAD(4, 1);
            MFMA4(a0, a1, st1[0], st1[1], st1[2], st1[3])
            LOADG(st1, 6)
            a0 = AREAD(5, 0); a1 = AREAD(5, 1);
            MFMA4(a0, a1, st0[0], st0[1], st0[2], st0[3])
            LOADG(st0, 7)
            a0 = AREAD(6, 0); a1 = AREAD(6, 1);
            MFMA4(a0, a1, st1[0], st1[1], st1[2], st1[3])
            a0 = AREAD(7, 0); a1 = AREAD(7, 1);
            MFMA4(a0, a1, st0[0], st0[1], st0[2], st0[3])
        }

        // gates + state update (lane owns (b = mt*16+q*4+r, j = jh))
        _Float16 hn16[2][4];
#pragma unroll
        for (int mt = 0; mt < 2; ++mt) {
#pragma unroll
            for (int r = 0; r < 4; ++r) {
                float g  = ftanh(acc[mt][0][r]);
                float ii = fsig (acc[mt][1][r]);
                float f  = fsig (acc[mt][2][r]);
                float o  = fsig (acc[mt][3][r]);
                float cn = g * ii + cst[mt][r] * f;
                cst[mt][r] = cn;
                hn16[mt][r] = (_Float16)(ftanh(cn) * o);
            }
        }

        __syncthreads();   // B1: all A-frag reads of old h complete
#pragma unroll
        for (int mt = 0; mt < 2; ++mt)
#pragma unroll
            for (int r = 0; r < 4; ++r)
                hfrag[wbase + mt * 4096 + r * 8] = hn16[mt][r];
        if (tid < 32) xs[tid] = xnext;
        __syncthreads();   // B2: h_new visible for next step
    }

    // ---- epilogue: out = h_T @ W_ph + b_p ; wave w handles rows 2w, 2w+1 ----
#pragma unroll
    for (int rr = 0; rr < 2; ++rr) {
        int b = w * 2 + rr;
        int mt = b >> 4, m = b & 15;
        float hv[4];
#pragma unroll
        for (int a = 0; a < 4; ++a) {
            int j = lane + a * 64;
            int idx = ((mt * 8 + (j >> 5)) * 64 + ((j >> 3) & 3) * 16 + m) * 8 + (j & 7);
            hv[a] = (float)hfrag[idx];
        }
#pragma unroll
        for (int c = 0; c < CC; ++c) {
            float s = 0.f;
#pragma unroll
            for (int a = 0; a < 4; ++a) s += hv[a] * Wp[(lane + a * 64) * CC + c];
#pragma unroll
            for (int off = 32; off > 0; off >>= 1) s += __shfl_xor(s, off, 64);
            if (lane == 0) out[(b0 + b) * CC + c] = s + bp[c];
        }
    }
}

extern "C" void kernel_launch(void* const* d_in, const int* in_sizes, int n_in,
                              void* d_out, int out_size, void* d_ws, size_t ws_size,
                              hipStream_t stream) {
    (void)in_sizes; (void)n_in; (void)out_size; (void)ws_size; // needs ws_size >= 524288
    const float* x   = (const float*)d_in[0];
    const float* Wgx = (const float*)d_in[1];
    const float* Wgh = (const float*)d_in[2];
    const float* Wix = (const float*)d_in[3];
    const float* Wih = (const float*)d_in[4];
    const float* Wfx = (const float*)d_in[5];
    const float* Wfh = (const float*)d_in[6];
    const float* Wox = (const float*)d_in[7];
    const float* Woh = (const float*)d_in[8];
    const float* Wp  = (const float*)d_in[9];
    const float* bg  = (const float*)d_in[10];
    const float* bi  = (const float*)d_in[11];
    const float* bf  = (const float*)d_in[12];
    const float* bo  = (const float*)d_in[13];
    const float* bp  = (const float*)d_in[14];
    _Float16* wsW = (_Float16*)d_ws;

    pack_weights<<<128, 256, 0, stream>>>(Wgh, Wih, Wfh, Woh, wsW);

    hipFuncSetAttribute((const void*)lstm_main,
                        hipFuncAttributeMaxDynamicSharedMemorySize, LDS_TOTAL);
    lstm_main<<<256, 1024, LDS_TOTAL, stream>>>(
        x, wsW, Wgx, Wix, Wfx, Wox, bg, bi, bf, bo, Wp, bp, (float*)d_out);
}

// Round 3
// 23599.524 us; speedup vs baseline: 1.0917x; 1.0917x over previous
//
#include <hip/hip_runtime.h>

// LSTM: B=8192, T=2048, D=1, H=256, C=10
// Persistent: 256 WGs x 1024 threads (one/CU), 32 batch rows per WG.
// Per step: (32x256)@(256x1024) via v_mfma_f32_16x16x32_f16.
// Weight residency (8 kk-groups of K=32): kk=0,1 in VGPRs (32 regs),
// kk=2 resident in LDS (64 KB), kk=3..7 streamed from L2 via
// global_load_lds into a 3-slot x 16 KB LDS ring (per-wave self-staged
// chunks, s_waitcnt vmcnt(1) discipline, no barrier coupling).
// h double-buffered in LDS (MFMA-A-frag order) -> ONE raw
// lgkmcnt(0)+s_barrier per step (stream loads survive the barrier).
// amdgpu_waves_per_eu(4,4) pins 4 waves/EU -> 128-VGPR budget, no spills.
// d_ws: 512 KB fp16 B-frags, byte off = ((kk*16+w)*4+t)*1024 + lane*16.

#define BB 8192
#define TT 2048
#define HH 256
#define CC 10

typedef _Float16 half8 __attribute__((ext_vector_type(8)));
typedef float float4v __attribute__((ext_vector_type(4)));

// LDS map (bytes)
#define WRES_OFF   0                    // kk=2 resident: 64 KB
#define RING_OFF   65536                // 3 slots x 16384
#define RING_SLOT  16384
#define H_OFF      114688               // 2 x 16384 (h double buffer)
#define XS_OFF     147456               // 2 x 128
#define LDS_TOTAL  147712

__device__ __forceinline__ float frcp(float v)  { return __builtin_amdgcn_rcpf(v); }
__device__ __forceinline__ float fex2(float v)  { return __builtin_amdgcn_exp2f(v); }
__device__ __forceinline__ float fsig(float v)  { return frcp(1.0f + fex2(-1.442695040888963f * v)); }
__device__ __forceinline__ float ftanh(float v) { return 2.0f * frcp(1.0f + fex2(-2.885390081777927f * v)) - 1.0f; }

__device__ __forceinline__ void stream_issue(const void* g, void* l) {
    __builtin_amdgcn_global_load_lds((const __attribute__((address_space(1))) void*)g,
                                     (__attribute__((address_space(3))) void*)l, 16, 0, 0);
}
#define WAIT_VM1()     asm volatile("s_waitcnt vmcnt(1)" ::: "memory")
#define STEP_BARRIER() asm volatile("s_waitcnt lgkmcnt(0)\n\ts_barrier" ::: "memory")

// Pack W_{g,i,f,o}h (fp32 [256][256], row k, col j) into fp16 MFMA B-frag order.
// unit u = ((kk*16+w)*4+t)*64 + lane ; elem j: k = kk*32 + (lane>>4)*8 + j,
// gate t, hidden col j_h = w*16 + (lane&15).
__global__ void pack_weights(const float* __restrict__ Wg, const float* __restrict__ Wi,
                             const float* __restrict__ Wf, const float* __restrict__ Wo,
                             _Float16* __restrict__ wsW) {
    int u = blockIdx.x * blockDim.x + threadIdx.x;   // 32768 units
    int kk = u >> 12, rem = u & 4095;
    int w = rem >> 8, rem2 = rem & 255;
    int t = rem2 >> 6, lane = rem2 & 63;
    int q = lane >> 4, l15 = lane & 15;
    int jh = w * 16 + l15;
    const float* Wsrc = (t == 0) ? Wg : (t == 1) ? Wi : (t == 2) ? Wf : Wo;
    half8 v;
#pragma unroll
    for (int j = 0; j < 8; ++j) {
        int k = kk * 32 + q * 8 + j;
        v[j] = (_Float16)Wsrc[k * HH + jh];
    }
    ((half8*)wsW)[u] = v;
}

#define MFMA_T4(A0, A1, B0, B1, B2, B3)                                             \
    acc[0][0] = __builtin_amdgcn_mfma_f32_16x16x32_f16(A0, B0, acc[0][0], 0, 0, 0); \
    acc[1][0] = __builtin_amdgcn_mfma_f32_16x16x32_f16(A1, B0, acc[1][0], 0, 0, 0); \
    acc[0][1] = __builtin_amdgcn_mfma_f32_16x16x32_f16(A0, B1, acc[0][1], 0, 0, 0); \
    acc[1][1] = __builtin_amdgcn_mfma_f32_16x16x32_f16(A1, B1, acc[1][1], 0, 0, 0); \
    acc[0][2] = __builtin_amdgcn_mfma_f32_16x16x32_f16(A0, B2, acc[0][2], 0, 0, 0); \
    acc[1][2] = __builtin_amdgcn_mfma_f32_16x16x32_f16(A1, B2, acc[1][2], 0, 0, 0); \
    acc[0][3] = __builtin_amdgcn_mfma_f32_16x16x32_f16(A0, B3, acc[0][3], 0, 0, 0); \
    acc[1][3] = __builtin_amdgcn_mfma_f32_16x16x32_f16(A1, B3, acc[1][3], 0, 0, 0);

#define AREAD(base, kkv, mtv) (*(const half8*)((base) + (mtv) * 4096 + (kkv) * 512 + lane * 8))

__attribute__((amdgpu_waves_per_eu(4, 4)))
__global__ void __launch_bounds__(1024) lstm_main(
    const float* __restrict__ x, const _Float16* __restrict__ wsW,
    const float* __restrict__ Wgx, const float* __restrict__ Wix,
    const float* __restrict__ Wfx, const float* __restrict__ Wox,
    const float* __restrict__ bg, const float* __restrict__ bi,
    const float* __restrict__ bfp, const float* __restrict__ bo,
    const float* __restrict__ Wp, const float* __restrict__ bp,
    float* __restrict__ out)
{
    extern __shared__ char smem[];
    _Float16* Wlds   = (_Float16*)(smem + WRES_OFF);
    _Float16* hfrag0 = (_Float16*)(smem + H_OFF);
    float*    xs     = (float*)(smem + XS_OFF);

    const int tid  = threadIdx.x;
    const int w    = tid >> 6;
    const int lane = tid & 63;
    const int q    = lane >> 4;
    const int l15  = lane & 15;
    const int jh   = w * 16 + l15;
    const int b0   = blockIdx.x * 32;

    // ---- prologue ----
    for (int i = tid; i < 8192; i += 1024) hfrag0[i] = (_Float16)0.f;   // h0 buf0
    if (tid < 32) xs[tid] = x[(b0 + tid) * TT + 0];
    {   // stage kk=2 into LDS (frag layout preserved)
        const uint4* src = (const uint4*)((const char*)wsW + 2 * 65536);
        uint4* dst = (uint4*)Wlds;
        for (int i = tid; i < 65536 / 16; i += 1024) dst[i] = src[i];
    }
    const char* wl  = (const char*)wsW + w * 4096 + lane * 16;     // per-lane global frag base
    char* ringw = smem + RING_OFF + w * 1024 + lane * 16;          // per-lane ring write base
    const _Float16* ringr = (const _Float16*)(smem + RING_OFF) + w * 512 + lane * 8;

    half8 wr[8];                                                   // kk=0,1 resident: 32 VGPRs
#pragma unroll
    for (int kk = 0; kk < 2; ++kk)
#pragma unroll
        for (int tt = 0; tt < 4; ++tt)
            wr[kk * 4 + tt] = *(const half8*)(wl + kk * 65536 + tt * 1024);

    const float wxv[4] = { Wgx[jh], Wix[jh], Wfx[jh], Wox[jh] };
    const float bv[4]  = { bg[jh],  bi[jh],  bfp[jh], bo[jh]  };
    float4v cst[2]; cst[0] = (float4v){0.f,0.f,0.f,0.f}; cst[1] = (float4v){0.f,0.f,0.f,0.f};

    // h-write scatter (frag order)
    const int kkw   = w >> 1;
    const int qp    = ((w & 1) << 1) | (l15 >> 3);
    const int j3    = l15 & 7;
    const int wbase = (kkw * 64 + qp * 16 + q * 4) * 8 + j3;       // + mt*4096 + r*8

    // prime ring: chunks 0,1 (kk=3, t=0,1) into slots 0,1
    stream_issue(wl + 3 * 65536 + 0 * 1024, ringw + 0 * RING_SLOT);
    stream_issue(wl + 3 * 65536 + 1 * 1024, ringw + 1 * RING_SLOT);
    int slot = 0;

    __syncthreads();

    // ---- time loop ----
#pragma unroll 1
    for (int ts = 0; ts < TT; ++ts) {
        const _Float16* hr = hfrag0 + (ts & 1) * 8192;
        _Float16*       hw = hfrag0 + ((ts + 1) & 1) * 8192;
        const float*    xr = xs + (ts & 1) * 32;
        float*          xw = xs + ((ts + 1) & 1) * 32;

        // acc init = bias + x_t * W_x (fp32, exact)
        float4v acc[2][4];
#pragma unroll
        for (int mt = 0; mt < 2; ++mt)
#pragma unroll
            for (int r = 0; r < 4; ++r) {
                float xvr = xr[mt * 16 + q * 4 + r];
#pragma unroll
                for (int tt = 0; tt < 4; ++tt)
                    acc[mt][tt][r] = bv[tt] + xvr * wxv[tt];
            }

        // resident K: kk=0,1 (VGPR), kk=2 (LDS)
        half8 a0 = AREAD(hr, 0, 0), a1 = AREAD(hr, 0, 1);
        MFMA_T4(a0, a1, wr[0], wr[1], wr[2], wr[3])
        a0 = AREAD(hr, 1, 0); a1 = AREAD(hr, 1, 1);
        MFMA_T4(a0, a1, wr[4], wr[5], wr[6], wr[7])
        a0 = AREAD(hr, 2, 0); a1 = AREAD(hr, 2, 1);
        {
            const _Float16* wb = Wlds + w * 2048 + lane * 8;
            MFMA_T4(a0, a1, *(const half8*)(wb), *(const half8*)(wb + 512),
                    *(const half8*)(wb + 1024), *(const half8*)(wb + 1536))
        }

        // streamed K: kk=3..7 via LDS ring, chunk=(kk,t), depth-2 prefetch
        float xnext = 0.f;
        const int tn = (ts + 1 < TT) ? (ts + 1) : (TT - 1);
#pragma unroll
        for (int kk = 3; kk <= 7; ++kk) {
            a0 = AREAD(hr, kk, 0); a1 = AREAD(hr, kk, 1);
#pragma unroll
            for (int t = 0; t < 4; ++t) {
                WAIT_VM1();                                   // chunk c complete
                const half8 bf = *(const half8*)(ringr + slot * 8192);
                // issue chunk c+2 (wraps to next step's chunks; weights are step-invariant)
                {
                    int c  = (kk - 3) * 4 + t;
                    int cn = c + 2; if (cn >= 20) cn -= 20;
                    int kkn = 3 + (cn >> 2), ttn = cn & 3;
                    int islot = slot + 2; if (islot >= 3) islot -= 3;
                    stream_issue(wl + kkn * 65536 + ttn * 1024, ringw + islot * RING_SLOT);
                }
                acc[0][t] = __builtin_amdgcn_mfma_f32_16x16x32_f16(a0, bf, acc[0][t], 0, 0, 0);
                acc[1][t] = __builtin_amdgcn_mfma_f32_16x16x32_f16(a1, bf, acc[1][t], 0, 0, 0);
                slot = (slot + 1 == 3) ? 0 : slot + 1;
                if (kk == 5 && t == 0) {                      // x prefetch mid-loop
                    if (tid < 32) xnext = x[(b0 + tid) * TT + tn];
                }
            }
        }

        // gates + state update (lane owns rows mt*16+q*4+r, col jh)
        _Float16 hn16[2][4];
#pragma unroll
        for (int mt = 0; mt < 2; ++mt)
#pragma unroll
            for (int r = 0; r < 4; ++r) {
                float g  = ftanh(acc[mt][0][r]);
                float ii = fsig (acc[mt][1][r]);
                float f  = fsig (acc[mt][2][r]);
                float o  = fsig (acc[mt][3][r]);
                float cn = g * ii + cst[mt][r] * f;
                cst[mt][r] = cn;
                hn16[mt][r] = (_Float16)(ftanh(cn) * o);
            }

        // write new h to the OTHER buffer (no pre-barrier needed)
#pragma unroll
        for (int mt = 0; mt < 2; ++mt)
#pragma unroll
            for (int r = 0; r < 4; ++r)
                hw[wbase + mt * 4096 + r * 8] = hn16[mt][r];
        if (tid < 32) xw[tid] = xnext;

        STEP_BARRIER();   // lgkmcnt(0) + s_barrier (stream loads stay in flight)
    }

    // ---- epilogue: out = h_T @ W_ph + b_p ; final h is in buf0 ----
#pragma unroll
    for (int rr = 0; rr < 2; ++rr) {
        int b = w * 2 + rr;
        int mt = b >> 4, m = b & 15;
        float hv[4];
#pragma unroll
        for (int a = 0; a < 4; ++a) {
            int j = lane + a * 64;
            int idx = ((mt * 8 + (j >> 5)) * 64 + ((j >> 3) & 3) * 16 + m) * 8 + (j & 7);
            hv[a] = (float)hfrag0[idx];
        }
#pragma unroll
        for (int c = 0; c < CC; ++c) {
            float s = 0.f;
#pragma unroll
            for (int a = 0; a < 4; ++a) s += hv[a] * Wp[(lane + a * 64) * CC + c];
#pragma unroll
            for (int off = 32; off > 0; off >>= 1) s += __shfl_xor(s, off, 64);
            if (lane == 0) out[(b0 + b) * CC + c] = s + bp[c];
        }
    }
}

extern "C" void kernel_launch(void* const* d_in, const int* in_sizes, int n_in,
                              void* d_out, int out_size, void* d_ws, size_t ws_size,
                              hipStream_t stream) {
    (void)in_sizes; (void)n_in; (void)out_size; (void)ws_size; // needs ws_size >= 524288
    const float* x   = (const float*)d_in[0];
    const float* Wgx = (const float*)d_in[1];
    const float* Wgh = (const float*)d_in[2];
    const float* Wix = (const float*)d_in[3];
    const float* Wih = (const float*)d_in[4];
    const float* Wfx = (const float*)d_in[5];
    const float* Wfh = (const float*)d_in[6];
    const float* Wox = (const float*)d_in[7];
    const float* Woh = (const float*)d_in[8];
    const float* Wp  = (const float*)d_in[9];
    const float* bg  = (const float*)d_in[10];
    const float* bi  = (const float*)d_in[11];
    const float* bf  = (const float*)d_in[12];
    const float* bo  = (const float*)d_in[13];
    const float* bp  = (const float*)d_in[14];
    _Float16* wsW = (_Float16*)d_ws;

    pack_weights<<<128, 256, 0, stream>>>(Wgh, Wih, Wfh, Woh, wsW);

    hipFuncSetAttribute((const void*)lstm_main,
                        hipFuncAttributeMaxDynamicSharedMemorySize, LDS_TOTAL);
    lstm_main<<<256, 1024, LDS_TOTAL, stream>>>(
        x, wsW, Wgx, Wix, Wfx, Wox, bg, bi, bf, bo, Wp, bp, (float*)d_out);
}